// Round 4
// baseline (459.035 us; speedup 1.0000x reference)
//
#include <hip/hip_runtime.h>
#include <math.h>

#define BATCH 2
#define SEQ   2048
#define HID   1024
#define NHEAD 16
#define DHEAD 64
#define MROWS (BATCH*SEQ)      // 4096
#define QK_SCALE 0.125f        // 1/sqrt(64)

typedef __attribute__((ext_vector_type(8))) short short8;
typedef __attribute__((ext_vector_type(4))) short short4v;
typedef __attribute__((ext_vector_type(4))) float floatx4;
#define MFMA16(a,b,c) __builtin_amdgcn_mfma_f32_16x16x32_bf16(a,b,c,0,0,0)

__device__ __forceinline__ unsigned short f2bf(float x) {   // round-half-up
    union { float f; unsigned u; } v; v.f = x;
    return (unsigned short)((v.u + 0x8000u) >> 16);
}
__device__ __forceinline__ float bf2f(unsigned short s) {
    union { unsigned u; float f; } v; v.u = ((unsigned)s) << 16;
    return v.f;
}
// pack two fp32 -> one dword of two bf16 (lo->low short), round-half-up
__device__ __forceinline__ unsigned pack_bf16(float lo, float hi) {
    union { float f; unsigned u; } a, b; a.f = lo; b.f = hi;
    return __builtin_amdgcn_perm(b.u + 0x8000u, a.u + 0x8000u, 0x07060302u);
}

// ---------------------------------------------------------------------------
// 4x W[K][N] fp32 -> Wt[N][K] bf16 in one launch (blockIdx.z selects W)
// ---------------------------------------------------------------------------
__global__ __launch_bounds__(256) void wtrans_kernel(
    const float* __restrict__ W0, const float* __restrict__ W1,
    const float* __restrict__ W2, const float* __restrict__ W3,
    unsigned short* __restrict__ T0, unsigned short* __restrict__ T1,
    unsigned short* __restrict__ T2, unsigned short* __restrict__ T3)
{
    const float* W; unsigned short* Wt;
    switch (blockIdx.z) {
        case 0: W = W0; Wt = T0; break;
        case 1: W = W1; Wt = T1; break;
        case 2: W = W2; Wt = T2; break;
        default: W = W3; Wt = T3; break;
    }
    __shared__ float T[64][68];
    const int tid = threadIdx.x;
    const int k0 = blockIdx.x * 64, n0 = blockIdx.y * 64;
#pragma unroll
    for (int it = 0; it < 4; it++) {
        const int id = it * 256 + tid;
        const int r = id >> 4, c4 = (id & 15) << 2;
        *(float4*)&T[r][c4] = *(const float4*)&W[(size_t)(k0 + r) * HID + n0 + c4];
    }
    __syncthreads();
#pragma unroll
    for (int it = 0; it < 2; it++) {
        const int id = it * 256 + tid;
        const int n = id >> 3, k8 = (id & 7) << 3;
        uint4 u;
        u.x = pack_bf16(T[k8 + 0][n], T[k8 + 1][n]);
        u.y = pack_bf16(T[k8 + 2][n], T[k8 + 3][n]);
        u.z = pack_bf16(T[k8 + 4][n], T[k8 + 5][n]);
        u.w = pack_bf16(T[k8 + 6][n], T[k8 + 7][n]);
        *(uint4*)&Wt[(size_t)(n0 + n) * HID + k0 + k8] = u;
    }
}

// ---------------------------------------------------------------------------
// vb[B*SEQ][HID] bf16 -> vt[B][NH][DH][SEQ] bf16 (per-head transpose)
// ---------------------------------------------------------------------------
__global__ __launch_bounds__(256) void vtrans_kernel(
    const unsigned short* __restrict__ vb, unsigned short* __restrict__ vt)
{
    __shared__ unsigned short T[64][72];
    const int b = blockIdx.z, h = blockIdx.y, l0 = blockIdx.x * 64;
    const int tid = threadIdx.x;
#pragma unroll
    for (int it = 0; it < 2; it++) {
        const int id = it * 256 + tid;
        const int l = id >> 3, c8 = (id & 7) << 3;
        *(uint4*)&T[l][c8] =
            *(const uint4*)&vb[(size_t)(b * SEQ + l0 + l) * HID + h * DHEAD + c8];
    }
    __syncthreads();
#pragma unroll
    for (int it = 0; it < 2; it++) {
        const int id = it * 256 + tid;
        const int d = id >> 3, l8 = (id & 7) << 3;
        ushort4 u0, u1;
        u0.x = T[l8 + 0][d]; u0.y = T[l8 + 1][d];
        u0.z = T[l8 + 2][d]; u0.w = T[l8 + 3][d];
        u1.x = T[l8 + 4][d]; u1.y = T[l8 + 5][d];
        u1.z = T[l8 + 6][d]; u1.w = T[l8 + 7][d];
        const size_t o = ((size_t)(b * NHEAD + h) * DHEAD + d) * SEQ + l0 + l8;
        *(ushort4*)&vt[o] = u0;
        *(ushort4*)&vt[o + 4] = u1;
    }
}

// ---------------------------------------------------------------------------
// MFMA GEMM, 128x128 tile, BK=64. A from fp32 (converted in staging) or bf16
// (with optional row-gate). B pre-transposed bf16 [N][K]. fp32 accumulate.
// ---------------------------------------------------------------------------
__global__ __launch_bounds__(256) void gemm_mfma_kernel(
    const float* __restrict__ Af, const unsigned short* __restrict__ Ab,
    const unsigned short* __restrict__ Bt, const float* __restrict__ bias,
    const float* __restrict__ gate_cs, const float* __restrict__ gate_th,
    float* __restrict__ Cf, unsigned short* __restrict__ Cb,
    int M, int N, int K)
{
    __shared__ unsigned short As[128][72];
    __shared__ unsigned short Bs[128][72];
    const int tid = threadIdx.x;
    const int w = tid >> 6, lane = tid & 63;
    const int c = lane & 15, quad = lane >> 4;
    const int m0 = blockIdx.x * 128, n0 = blockIdx.y * 128;
    const int wm = (w >> 1) * 64, wn = (w & 1) * 64;

    // gate per staged row (final GEMM only) — rows are loop-invariant
    bool grow[4] = {true, true, true, true};
    if (gate_cs) {
#pragma unroll
        for (int it = 0; it < 4; it++) {
            const int r = (it * 256 + tid) >> 3;
            grow[it] = (gate_cs[m0 + r] - gate_th[m0 + r]) > 0.f;
        }
    }

    floatx4 acc[4][4];
#pragma unroll
    for (int i = 0; i < 4; i++)
#pragma unroll
        for (int j = 0; j < 4; j++) acc[i][j] = (floatx4){0.f, 0.f, 0.f, 0.f};

    for (int kc = 0; kc < K; kc += 64) {
        __syncthreads();
#pragma unroll
        for (int it = 0; it < 4; it++) {
            const int id = it * 256 + tid;
            const int r = id >> 3, c8 = (id & 7) << 3;
            uint4 u;
            if (Af) {
                const float* src = &Af[(size_t)(m0 + r) * K + kc + c8];
                const float4 f0 = *(const float4*)src;
                const float4 f1 = *(const float4*)(src + 4);
                u.x = pack_bf16(f0.x, f0.y); u.y = pack_bf16(f0.z, f0.w);
                u.z = pack_bf16(f1.x, f1.y); u.w = pack_bf16(f1.z, f1.w);
            } else {
                u = *(const uint4*)&Ab[(size_t)(m0 + r) * K + kc + c8];
                if (!grow[it]) { u.x = 0; u.y = 0; u.z = 0; u.w = 0; }
            }
            *(uint4*)&As[r][c8] = u;
            *(uint4*)&Bs[r][c8] = *(const uint4*)&Bt[(size_t)(n0 + r) * K + kc + c8];
        }
        __syncthreads();
#pragma unroll
        for (int kk = 0; kk < 2; kk++) {
            short8 af[4], bf[4];
#pragma unroll
            for (int mt = 0; mt < 4; mt++)
                af[mt] = *(const short8*)&As[wm + mt * 16 + c][kk * 32 + quad * 8];
#pragma unroll
            for (int nt = 0; nt < 4; nt++)
                bf[nt] = *(const short8*)&Bs[wn + nt * 16 + c][kk * 32 + quad * 8];
#pragma unroll
            for (int mt = 0; mt < 4; mt++)
#pragma unroll
                for (int nt = 0; nt < 4; nt++)
                    acc[mt][nt] = MFMA16(af[mt], bf[nt], acc[mt][nt]);
        }
    }

#pragma unroll
    for (int nt = 0; nt < 4; nt++) {
        const int n = n0 + wn + nt * 16 + c;
        const float bb = bias[n];
#pragma unroll
        for (int mt = 0; mt < 4; mt++) {
            const int m = m0 + wm + mt * 16 + quad * 4;
#pragma unroll
            for (int r = 0; r < 4; r++) {
                const float val = acc[mt][nt][r] + bb;
                const size_t off = (size_t)(m + r) * N + n;
                if (Cf) Cf[off] = val;
                if (Cb) Cb[off] = f2bf(val);
            }
        }
    }
}

// ---------------------------------------------------------------------------
// threshold[row] = sum_h qb*kb*Wt + bt  (bf16 inputs, fp32 accumulate)
// ---------------------------------------------------------------------------
__global__ __launch_bounds__(256) void threshold_kernel(
    const unsigned short* __restrict__ qb, const unsigned short* __restrict__ kb,
    const float* __restrict__ Wt, const float* __restrict__ bt,
    float* __restrict__ thr)
{
    const int w = threadIdx.x >> 6, lane = threadIdx.x & 63;
    const int row = blockIdx.x * 4 + w;
    const unsigned short* qr = qb + (size_t)row * HID;
    const unsigned short* kr = kb + (size_t)row * HID;
    float s = 0.f;
#pragma unroll
    for (int ii = 0; ii < 2; ii++) {
        const int base = ii * 512 + lane * 8;
        const ushort4 q0 = *(const ushort4*)&qr[base];
        const ushort4 q1 = *(const ushort4*)&qr[base + 4];
        const ushort4 k0 = *(const ushort4*)&kr[base];
        const ushort4 k1 = *(const ushort4*)&kr[base + 4];
        const float4 w0 = *(const float4*)&Wt[base];
        const float4 w1 = *(const float4*)&Wt[base + 4];
        s += bf2f(q0.x) * bf2f(k0.x) * w0.x + bf2f(q0.y) * bf2f(k0.y) * w0.y +
             bf2f(q0.z) * bf2f(k0.z) * w0.z + bf2f(q0.w) * bf2f(k0.w) * w0.w +
             bf2f(q1.x) * bf2f(k1.x) * w1.x + bf2f(q1.y) * bf2f(k1.y) * w1.y +
             bf2f(q1.z) * bf2f(k1.z) * w1.z + bf2f(q1.w) * bf2f(k1.w) * w1.w;
    }
#pragma unroll
    for (int off = 32; off > 0; off >>= 1) s += __shfl_xor(s, off, 64);
    if (lane == 0) thr[row] = s + bt[0];
}

// ---------------------------------------------------------------------------
// Pass 1 (MFMA): per (b,h), 64 q-rows/block. No max-subtraction (|s|<~3).
// Mask folded as additive bias into expf. Ps stride=68 -> conflict-free b16
// writes; A-frag reads via 2x b64. Q frags hoisted out of the k-loop.
// ---------------------------------------------------------------------------
__global__ __launch_bounds__(256) void flash_mfma_kernel(
    const unsigned short* __restrict__ qb, const unsigned short* __restrict__ kb,
    const unsigned short* __restrict__ vt, const unsigned char* __restrict__ mask,
    unsigned short* __restrict__ att, float* __restrict__ zinv_out)
{
    const int b = blockIdx.z, h = blockIdx.y;
    const int q0 = blockIdx.x * 64;
    const int tid = threadIdx.x;
    const int w = tid >> 6, lane = tid & 63;
    const int c = lane & 15, quad = lane >> 4;

    __shared__ unsigned short Qs[64][72];
    __shared__ unsigned short Ks[64][72];
    __shared__ unsigned short Vs[64][72];   // Vs[d][j]
    __shared__ unsigned short Ps[4][16][68];
    __shared__ float mbf[64];

    const size_t hoff = (size_t)h * DHEAD;
    for (int g = tid; g < 512; g += 256) {
        const int r = g >> 3, c8 = (g & 7) << 3;
        *(uint4*)&Qs[r][c8] =
            *(const uint4*)&qb[(size_t)(b * SEQ + q0 + r) * HID + hoff + c8];
    }
    __syncthreads();
    const short8 aq0 = *(const short8*)&Qs[w * 16 + c][quad * 8];
    const short8 aq1 = *(const short8*)&Qs[w * 16 + c][32 + quad * 8];

    floatx4 acc_o[4];
#pragma unroll
    for (int dt = 0; dt < 4; dt++) acc_o[dt] = (floatx4){0.f, 0.f, 0.f, 0.f};
    float zp[4] = {0.f, 0.f, 0.f, 0.f};
    const size_t vtbase = (size_t)(b * NHEAD + h) * DHEAD * SEQ;

    for (int kc = 0; kc < SEQ; kc += 64) {
        __syncthreads();
        for (int g = tid; g < 512; g += 256) {
            const int r = g >> 3, c8 = (g & 7) << 3;
            *(uint4*)&Ks[r][c8] =
                *(const uint4*)&kb[(size_t)(b * SEQ + kc + r) * HID + hoff + c8];
            *(uint4*)&Vs[r][c8] =
                *(const uint4*)&vt[vtbase + (size_t)r * SEQ + kc + c8];
        }
        if (tid < 64) mbf[tid] = mask[(size_t)b * SEQ + kc + tid] ? -1e9f : 0.f;
        __syncthreads();

#pragma unroll
        for (int nt = 0; nt < 4; nt++) {
            const short8 bk0 = *(const short8*)&Ks[nt * 16 + c][quad * 8];
            const short8 bk1 = *(const short8*)&Ks[nt * 16 + c][32 + quad * 8];
            floatx4 s = (floatx4){0.f, 0.f, 0.f, 0.f};
            s = MFMA16(aq0, bk0, s);
            s = MFMA16(aq1, bk1, s);
            const float mb = mbf[nt * 16 + c];
#pragma unroll
            for (int r = 0; r < 4; r++) {
                const float p = __expf(fmaf(s[r], QK_SCALE, mb));
                zp[r] += p;
                Ps[w][quad * 4 + r][nt * 16 + c] = f2bf(p);
            }
        }

        short4v p00 = *(const short4v*)&Ps[w][c][quad * 8];
        short4v p01 = *(const short4v*)&Ps[w][c][quad * 8 + 4];
        short4v p10 = *(const short4v*)&Ps[w][c][32 + quad * 8];
        short4v p11 = *(const short4v*)&Ps[w][c][32 + quad * 8 + 4];
        const short8 ap0 = __builtin_shufflevector(p00, p01, 0, 1, 2, 3, 4, 5, 6, 7);
        const short8 ap1 = __builtin_shufflevector(p10, p11, 0, 1, 2, 3, 4, 5, 6, 7);
#pragma unroll
        for (int dt = 0; dt < 4; dt++) {
            const short8 bv0 = *(const short8*)&Vs[dt * 16 + c][quad * 8];
            const short8 bv1 = *(const short8*)&Vs[dt * 16 + c][32 + quad * 8];
            acc_o[dt] = MFMA16(ap0, bv0, acc_o[dt]);
            acc_o[dt] = MFMA16(ap1, bv1, acc_o[dt]);
        }
    }

#pragma unroll
    for (int r = 0; r < 4; r++) {
        float z = zp[r];
        z += __shfl_xor(z, 1, 64); z += __shfl_xor(z, 2, 64);
        z += __shfl_xor(z, 4, 64); z += __shfl_xor(z, 8, 64);
        zp[r] = 1.0f / (z + 1e-30f);
    }

#pragma unroll
    for (int dt = 0; dt < 4; dt++)
#pragma unroll
        for (int r = 0; r < 4; r++)
            att[(size_t)(b * SEQ + q0 + w * 16 + quad * 4 + r) * HID + hoff +
                dt * 16 + c] = f2bf(acc_o[dt][r] * zp[r]);

    if (c == 0) {
        const size_t zb = (size_t)(b * NHEAD + h) * SEQ + q0 + w * 16 + quad * 4;
#pragma unroll
        for (int r = 0; r < 4; r++) zinv_out[zb + r] = zp[r];
    }
}

// ---------------------------------------------------------------------------
// Pass 2 (MFMA): colsum_k += sum_q exp(s)*zinv_q; atomicAdd over heads.
// K frags + per-row mask bias hoisted out of the q-loop.
// ---------------------------------------------------------------------------
__global__ __launch_bounds__(256) void colsum_mfma_kernel(
    const unsigned short* __restrict__ qb, const unsigned short* __restrict__ kb,
    const unsigned char* __restrict__ mask, const float* __restrict__ zinv,
    float* __restrict__ colsum)
{
    const int b = blockIdx.z, h = blockIdx.y, k0 = blockIdx.x * 64;
    const int tid = threadIdx.x;
    const int w = tid >> 6, lane = tid & 63;
    const int c = lane & 15, quad = lane >> 4;

    __shared__ unsigned short Ks[64][72];
    __shared__ unsigned short Qs[64][72];
    __shared__ float zs[64];

    const size_t hoff = (size_t)h * DHEAD;
    for (int g = tid; g < 512; g += 256) {
        const int r = g >> 3, c8 = (g & 7) << 3;
        *(uint4*)&Ks[r][c8] =
            *(const uint4*)&kb[(size_t)(b * SEQ + k0 + r) * HID + hoff + c8];
    }
    float mb[4];
#pragma unroll
    for (int r = 0; r < 4; r++)
        mb[r] = mask[(size_t)b * SEQ + k0 + w * 16 + quad * 4 + r] ? -1e9f : 0.f;
    __syncthreads();
    const short8 ak0 = *(const short8*)&Ks[w * 16 + c][quad * 8];
    const short8 ak1 = *(const short8*)&Ks[w * 16 + c][32 + quad * 8];

    float cs[4] = {0.f, 0.f, 0.f, 0.f};
    const size_t zbase = (size_t)(b * NHEAD + h) * SEQ;

    for (int qc = 0; qc < SEQ; qc += 64) {
        __syncthreads();
        for (int g = tid; g < 512; g += 256) {
            const int r = g >> 3, c8 = (g & 7) << 3;
            *(uint4*)&Qs[r][c8] =
                *(const uint4*)&qb[(size_t)(b * SEQ + qc + r) * HID + hoff + c8];
        }
        if (tid < 64) zs[tid] = zinv[zbase + qc + tid];
        __syncthreads();

#pragma unroll
        for (int qt = 0; qt < 4; qt++) {
            const short8 bq0 = *(const short8*)&Qs[qt * 16 + c][quad * 8];
            const short8 bq1 = *(const short8*)&Qs[qt * 16 + c][32 + quad * 8];
            floatx4 s = (floatx4){0.f, 0.f, 0.f, 0.f};
            s = MFMA16(ak0, bq0, s);
            s = MFMA16(ak1, bq1, s);
            const float zi = zs[qt * 16 + c];
#pragma unroll
            for (int r = 0; r < 4; r++)
                cs[r] += __expf(fmaf(s[r], QK_SCALE, mb[r])) * zi;
        }
    }

#pragma unroll
    for (int r = 0; r < 4; r++) {
        float v = cs[r];
        v += __shfl_xor(v, 1, 64); v += __shfl_xor(v, 2, 64);
        v += __shfl_xor(v, 4, 64); v += __shfl_xor(v, 8, 64);
        if (c == 0)
            atomicAdd(&colsum[(size_t)b * SEQ + k0 + w * 16 + quad * 4 + r], v);
    }
}

// ---------------------------------------------------------------------------
extern "C" void kernel_launch(void* const* d_in, const int* in_sizes, int n_in,
                              void* d_out, int out_size, void* d_ws, size_t ws_size,
                              hipStream_t stream)
{
    const float* v  = (const float*)d_in[0];
    const float* k  = (const float*)d_in[1];
    const float* q  = (const float*)d_in[2];
    const unsigned char* mask = (const unsigned char*)d_in[3];
    const float* Wv = (const float*)d_in[4];
    const float* bv = (const float*)d_in[5];
    const float* Wk = (const float*)d_in[6];
    const float* bk = (const float*)d_in[7];
    const float* Wq = (const float*)d_in[8];
    const float* bq = (const float*)d_in[9];
    const float* Wt = (const float*)d_in[10];
    const float* bt = (const float*)d_in[11];
    const float* Wm = (const float*)d_in[12];
    const float* bm = (const float*)d_in[13];
    float* out = (float*)d_out;

    const size_t NE = (size_t)MROWS * HID;
    const size_t WE = (size_t)HID * HID;
    unsigned short* qp   = (unsigned short*)d_ws;
    unsigned short* kp   = qp  + NE;
    unsigned short* vp   = kp  + NE;
    unsigned short* vtb  = vp  + NE;
    unsigned short* attb = vtb + NE;
    unsigned short* WqT  = attb + NE;
    unsigned short* WkT  = WqT + WE;
    unsigned short* WvT  = WkT + WE;
    unsigned short* WmT  = WvT + WE;
    float* thr    = (float*)(WmT + WE);
    float* zinv   = thr  + MROWS;
    float* colsum = zinv + (size_t)BATCH * NHEAD * SEQ;

    wtrans_kernel<<<dim3(HID / 64, HID / 64, 4), 256, 0, stream>>>(
        Wq, Wk, Wv, Wm, WqT, WkT, WvT, WmT);

    const dim3 gg(MROWS / 128, HID / 128);
    gemm_mfma_kernel<<<gg, 256, 0, stream>>>(q, nullptr, WqT, bq, nullptr, nullptr,
                                             nullptr, qp, MROWS, HID, HID);
    gemm_mfma_kernel<<<gg, 256, 0, stream>>>(k, nullptr, WkT, bk, nullptr, nullptr,
                                             nullptr, kp, MROWS, HID, HID);
    gemm_mfma_kernel<<<gg, 256, 0, stream>>>(v, nullptr, WvT, bv, nullptr, nullptr,
                                             nullptr, vp, MROWS, HID, HID);

    vtrans_kernel<<<dim3(SEQ / 64, NHEAD, BATCH), 256, 0, stream>>>(vp, vtb);

    threshold_kernel<<<MROWS / 4, 256, 0, stream>>>(qp, kp, Wt, bt, thr);

    flash_mfma_kernel<<<dim3(SEQ / 64, NHEAD, BATCH), 256, 0, stream>>>(
        qp, kp, vtb, mask, attb, zinv);

    hipMemsetAsync(colsum, 0, MROWS * sizeof(float), stream);
    colsum_mfma_kernel<<<dim3(SEQ / 64, NHEAD, BATCH), 256, 0, stream>>>(
        qp, kp, mask, zinv, colsum);

    gemm_mfma_kernel<<<gg, 256, 0, stream>>>(nullptr, attb, WmT, bm, colsum, thr,
                                             out, nullptr, MROWS, HID, HID);
}

// Round 5
// 340.855 us; speedup vs baseline: 1.3467x; 1.3467x over previous
//
#include <hip/hip_runtime.h>
#include <math.h>

#define BATCH 2
#define SEQ   2048
#define HID   1024
#define NHEAD 16
#define DHEAD 64
#define MROWS (BATCH*SEQ)      // 4096
#define QK_SCALE 0.125f        // 1/sqrt(64)

typedef __attribute__((ext_vector_type(8))) short short8;
typedef __attribute__((ext_vector_type(4))) short short4v;
typedef __attribute__((ext_vector_type(4))) float floatx4;
#define MFMA16(a,b,c) __builtin_amdgcn_mfma_f32_16x16x32_bf16(a,b,c,0,0,0)

__device__ __forceinline__ unsigned short f2bf(float x) {   // round-half-up
    union { float f; unsigned u; } v; v.f = x;
    return (unsigned short)((v.u + 0x8000u) >> 16);
}
__device__ __forceinline__ float bf2f(unsigned short s) {
    union { unsigned u; float f; } v; v.u = ((unsigned)s) << 16;
    return v.f;
}
// pack two fp32 -> one dword of two bf16 (lo->low short), round-half-up
__device__ __forceinline__ unsigned pack_bf16(float lo, float hi) {
    union { float f; unsigned u; } a, b; a.f = lo; b.f = hi;
    return __builtin_amdgcn_perm(b.u + 0x8000u, a.u + 0x8000u, 0x07060302u);
}

// ---------------------------------------------------------------------------
// fp32 -> bf16 bulk convert; blockIdx.y selects among 3 tensors
// ---------------------------------------------------------------------------
__global__ __launch_bounds__(256) void cvt_bf16_kernel(
    const float* __restrict__ i0, const float* __restrict__ i1,
    const float* __restrict__ i2,
    unsigned short* __restrict__ o0, unsigned short* __restrict__ o1,
    unsigned short* __restrict__ o2)
{
    const float* in; unsigned short* out;
    switch (blockIdx.y) {
        case 0:  in = i0; out = o0; break;
        case 1:  in = i1; out = o1; break;
        default: in = i2; out = o2; break;
    }
    const size_t i = ((size_t)blockIdx.x * 256 + threadIdx.x) * 8;
    const float4 a = *(const float4*)&in[i];
    const float4 b = *(const float4*)&in[i + 4];
    uint4 u;
    u.x = pack_bf16(a.x, a.y); u.y = pack_bf16(a.z, a.w);
    u.z = pack_bf16(b.x, b.y); u.w = pack_bf16(b.z, b.w);
    *(uint4*)&out[i] = u;
}

// ---------------------------------------------------------------------------
// 4x W[K][N] fp32 -> Wt[N][K] bf16 in one launch (blockIdx.z selects W)
// ---------------------------------------------------------------------------
__global__ __launch_bounds__(256) void wtrans_kernel(
    const float* __restrict__ W0, const float* __restrict__ W1,
    const float* __restrict__ W2, const float* __restrict__ W3,
    unsigned short* __restrict__ T0, unsigned short* __restrict__ T1,
    unsigned short* __restrict__ T2, unsigned short* __restrict__ T3)
{
    const float* W; unsigned short* Wt;
    switch (blockIdx.z) {
        case 0: W = W0; Wt = T0; break;
        case 1: W = W1; Wt = T1; break;
        case 2: W = W2; Wt = T2; break;
        default: W = W3; Wt = T3; break;
    }
    __shared__ float T[64][68];
    const int tid = threadIdx.x;
    const int k0 = blockIdx.x * 64, n0 = blockIdx.y * 64;
#pragma unroll
    for (int it = 0; it < 4; it++) {
        const int id = it * 256 + tid;
        const int r = id >> 4, c4 = (id & 15) << 2;
        *(float4*)&T[r][c4] = *(const float4*)&W[(size_t)(k0 + r) * HID + n0 + c4];
    }
    __syncthreads();
#pragma unroll
    for (int it = 0; it < 2; it++) {
        const int id = it * 256 + tid;
        const int n = id >> 3, k8 = (id & 7) << 3;
        uint4 u;
        u.x = pack_bf16(T[k8 + 0][n], T[k8 + 1][n]);
        u.y = pack_bf16(T[k8 + 2][n], T[k8 + 3][n]);
        u.z = pack_bf16(T[k8 + 4][n], T[k8 + 5][n]);
        u.w = pack_bf16(T[k8 + 6][n], T[k8 + 7][n]);
        *(uint4*)&Wt[(size_t)(n0 + n) * HID + k0 + k8] = u;
    }
}

// ---------------------------------------------------------------------------
// vb[B*SEQ][HID] bf16 -> vt[B][NH][DH][SEQ] bf16 (per-head transpose)
// ---------------------------------------------------------------------------
__global__ __launch_bounds__(256) void vtrans_kernel(
    const unsigned short* __restrict__ vb, unsigned short* __restrict__ vt)
{
    __shared__ unsigned short T[64][72];
    const int b = blockIdx.z, h = blockIdx.y, l0 = blockIdx.x * 64;
    const int tid = threadIdx.x;
#pragma unroll
    for (int it = 0; it < 2; it++) {
        const int id = it * 256 + tid;
        const int l = id >> 3, c8 = (id & 7) << 3;
        *(uint4*)&T[l][c8] =
            *(const uint4*)&vb[(size_t)(b * SEQ + l0 + l) * HID + h * DHEAD + c8];
    }
    __syncthreads();
#pragma unroll
    for (int it = 0; it < 2; it++) {
        const int id = it * 256 + tid;
        const int d = id >> 3, l8 = (id & 7) << 3;
        ushort4 u0, u1;
        u0.x = T[l8 + 0][d]; u0.y = T[l8 + 1][d];
        u0.z = T[l8 + 2][d]; u0.w = T[l8 + 3][d];
        u1.x = T[l8 + 4][d]; u1.y = T[l8 + 5][d];
        u1.z = T[l8 + 6][d]; u1.w = T[l8 + 7][d];
        const size_t o = ((size_t)(b * NHEAD + h) * DHEAD + d) * SEQ + l0 + l8;
        *(ushort4*)&vt[o] = u0;
        *(ushort4*)&vt[o + 4] = u1;
    }
}

// ---------------------------------------------------------------------------
// MFMA GEMM, 128x128 tile, BK=64, bf16 A/B, fp32 accumulate.
// Optional per-row gate on A (final GEMM). B pre-transposed bf16 [N][K].
// ---------------------------------------------------------------------------
__global__ __launch_bounds__(256) void gemm_mfma_kernel(
    const unsigned short* __restrict__ Ab, const unsigned short* __restrict__ Bt,
    const float* __restrict__ bias,
    const float* __restrict__ gate_cs, const float* __restrict__ gate_th,
    float* __restrict__ Cf, unsigned short* __restrict__ Cb,
    int M, int N, int K)
{
    __shared__ unsigned short As[128][72];
    __shared__ unsigned short Bs[128][72];
    const int tid = threadIdx.x;
    const int w = tid >> 6, lane = tid & 63;
    const int c = lane & 15, quad = lane >> 4;
    const int m0 = blockIdx.x * 128, n0 = blockIdx.y * 128;
    const int wm = (w >> 1) * 64, wn = (w & 1) * 64;

    bool grow[4] = {true, true, true, true};
    if (gate_cs) {
#pragma unroll
        for (int it = 0; it < 4; it++) {
            const int r = (it * 256 + tid) >> 3;
            grow[it] = (gate_cs[m0 + r] - gate_th[m0 + r]) > 0.f;
        }
    }

    floatx4 acc[4][4];
#pragma unroll
    for (int i = 0; i < 4; i++)
#pragma unroll
        for (int j = 0; j < 4; j++) acc[i][j] = (floatx4){0.f, 0.f, 0.f, 0.f};

    for (int kc = 0; kc < K; kc += 64) {
        __syncthreads();
#pragma unroll
        for (int it = 0; it < 4; it++) {
            const int id = it * 256 + tid;
            const int r = id >> 3, c8 = (id & 7) << 3;
            uint4 u = *(const uint4*)&Ab[(size_t)(m0 + r) * K + kc + c8];
            if (!grow[it]) { u.x = 0; u.y = 0; u.z = 0; u.w = 0; }
            *(uint4*)&As[r][c8] = u;
            *(uint4*)&Bs[r][c8] = *(const uint4*)&Bt[(size_t)(n0 + r) * K + kc + c8];
        }
        __syncthreads();
#pragma unroll
        for (int kk = 0; kk < 2; kk++) {
            short8 af[4], bf[4];
#pragma unroll
            for (int mt = 0; mt < 4; mt++)
                af[mt] = *(const short8*)&As[wm + mt * 16 + c][kk * 32 + quad * 8];
#pragma unroll
            for (int nt = 0; nt < 4; nt++)
                bf[nt] = *(const short8*)&Bs[wn + nt * 16 + c][kk * 32 + quad * 8];
#pragma unroll
            for (int mt = 0; mt < 4; mt++)
#pragma unroll
                for (int nt = 0; nt < 4; nt++)
                    acc[mt][nt] = MFMA16(af[mt], bf[nt], acc[mt][nt]);
        }
    }

#pragma unroll
    for (int nt = 0; nt < 4; nt++) {
        const int n = n0 + wn + nt * 16 + c;
        const float bb = bias[n];
#pragma unroll
        for (int mt = 0; mt < 4; mt++) {
            const int m = m0 + wm + mt * 16 + quad * 4;
#pragma unroll
            for (int r = 0; r < 4; r++) {
                const float val = acc[mt][nt][r] + bb;
                const size_t off = (size_t)(m + r) * N + n;
                if (Cf) Cf[off] = val;
                if (Cb) Cb[off] = f2bf(val);
            }
        }
    }
}

// ---------------------------------------------------------------------------
// threshold[row] = sum_h qb*kb*Wt + bt  (bf16 inputs, fp32 accumulate)
// ---------------------------------------------------------------------------
__global__ __launch_bounds__(256) void threshold_kernel(
    const unsigned short* __restrict__ qb, const unsigned short* __restrict__ kb,
    const float* __restrict__ Wt, const float* __restrict__ bt,
    float* __restrict__ thr)
{
    const int w = threadIdx.x >> 6, lane = threadIdx.x & 63;
    const int row = blockIdx.x * 4 + w;
    const unsigned short* qr = qb + (size_t)row * HID;
    const unsigned short* kr = kb + (size_t)row * HID;
    float s = 0.f;
#pragma unroll
    for (int ii = 0; ii < 2; ii++) {
        const int base = ii * 512 + lane * 8;
        const ushort4 q0 = *(const ushort4*)&qr[base];
        const ushort4 q1 = *(const ushort4*)&qr[base + 4];
        const ushort4 k0 = *(const ushort4*)&kr[base];
        const ushort4 k1 = *(const ushort4*)&kr[base + 4];
        const float4 w0 = *(const float4*)&Wt[base];
        const float4 w1 = *(const float4*)&Wt[base + 4];
        s += bf2f(q0.x) * bf2f(k0.x) * w0.x + bf2f(q0.y) * bf2f(k0.y) * w0.y +
             bf2f(q0.z) * bf2f(k0.z) * w0.z + bf2f(q0.w) * bf2f(k0.w) * w0.w +
             bf2f(q1.x) * bf2f(k1.x) * w1.x + bf2f(q1.y) * bf2f(k1.y) * w1.y +
             bf2f(q1.z) * bf2f(k1.z) * w1.z + bf2f(q1.w) * bf2f(k1.w) * w1.w;
    }
#pragma unroll
    for (int off = 32; off > 0; off >>= 1) s += __shfl_xor(s, off, 64);
    if (lane == 0) thr[row] = s + bt[0];
}

// ---------------------------------------------------------------------------
// Pass 1 (MFMA): 128 q-rows/block, 8 waves (16 rows each). No max-subtraction
// (|s|<~3). Mask folded as additive bias into expf. att written bf16.
// ---------------------------------------------------------------------------
__global__ __launch_bounds__(512) void flash_mfma_kernel(
    const unsigned short* __restrict__ qb, const unsigned short* __restrict__ kb,
    const unsigned short* __restrict__ vt, const unsigned char* __restrict__ mask,
    unsigned short* __restrict__ att, float* __restrict__ zinv_out)
{
    const int b = blockIdx.z, h = blockIdx.y;
    const int q0 = blockIdx.x * 128;
    const int tid = threadIdx.x;
    const int w = tid >> 6, lane = tid & 63;
    const int c = lane & 15, quad = lane >> 4;

    __shared__ unsigned short Qs[128][72];
    __shared__ unsigned short Ks[64][72];
    __shared__ unsigned short Vs[64][72];   // Vs[d][j]
    __shared__ unsigned short Ps[8][16][68];
    __shared__ float mbf[64];

    const size_t hoff = (size_t)h * DHEAD;
#pragma unroll
    for (int it = 0; it < 2; it++) {
        const int g = it * 512 + tid;
        const int r = g >> 3, c8 = (g & 7) << 3;
        *(uint4*)&Qs[r][c8] =
            *(const uint4*)&qb[(size_t)(b * SEQ + q0 + r) * HID + hoff + c8];
    }
    __syncthreads();
    const short8 aq0 = *(const short8*)&Qs[w * 16 + c][quad * 8];
    const short8 aq1 = *(const short8*)&Qs[w * 16 + c][32 + quad * 8];

    floatx4 acc_o[4];
#pragma unroll
    for (int dt = 0; dt < 4; dt++) acc_o[dt] = (floatx4){0.f, 0.f, 0.f, 0.f};
    float zp[4] = {0.f, 0.f, 0.f, 0.f};
    const size_t vtbase = (size_t)(b * NHEAD + h) * DHEAD * SEQ;

    for (int kc = 0; kc < SEQ; kc += 64) {
        __syncthreads();
        {
            const int r = tid >> 3, c8 = (tid & 7) << 3;
            *(uint4*)&Ks[r][c8] =
                *(const uint4*)&kb[(size_t)(b * SEQ + kc + r) * HID + hoff + c8];
            *(uint4*)&Vs[r][c8] =
                *(const uint4*)&vt[vtbase + (size_t)r * SEQ + kc + c8];
        }
        if (tid < 64) mbf[tid] = mask[(size_t)b * SEQ + kc + tid] ? -1e9f : 0.f;
        __syncthreads();

#pragma unroll
        for (int nt = 0; nt < 4; nt++) {
            const short8 bk0 = *(const short8*)&Ks[nt * 16 + c][quad * 8];
            const short8 bk1 = *(const short8*)&Ks[nt * 16 + c][32 + quad * 8];
            floatx4 s = (floatx4){0.f, 0.f, 0.f, 0.f};
            s = MFMA16(aq0, bk0, s);
            s = MFMA16(aq1, bk1, s);
            const float mb = mbf[nt * 16 + c];
#pragma unroll
            for (int r = 0; r < 4; r++) {
                const float p = __expf(fmaf(s[r], QK_SCALE, mb));
                zp[r] += p;
                Ps[w][quad * 4 + r][nt * 16 + c] = f2bf(p);
            }
        }

        short4v p00 = *(const short4v*)&Ps[w][c][quad * 8];
        short4v p01 = *(const short4v*)&Ps[w][c][quad * 8 + 4];
        short4v p10 = *(const short4v*)&Ps[w][c][32 + quad * 8];
        short4v p11 = *(const short4v*)&Ps[w][c][32 + quad * 8 + 4];
        const short8 ap0 = __builtin_shufflevector(p00, p01, 0, 1, 2, 3, 4, 5, 6, 7);
        const short8 ap1 = __builtin_shufflevector(p10, p11, 0, 1, 2, 3, 4, 5, 6, 7);
#pragma unroll
        for (int dt = 0; dt < 4; dt++) {
            const short8 bv0 = *(const short8*)&Vs[dt * 16 + c][quad * 8];
            const short8 bv1 = *(const short8*)&Vs[dt * 16 + c][32 + quad * 8];
            acc_o[dt] = MFMA16(ap0, bv0, acc_o[dt]);
            acc_o[dt] = MFMA16(ap1, bv1, acc_o[dt]);
        }
    }

#pragma unroll
    for (int r = 0; r < 4; r++) {
        float z = zp[r];
        z += __shfl_xor(z, 1, 64); z += __shfl_xor(z, 2, 64);
        z += __shfl_xor(z, 4, 64); z += __shfl_xor(z, 8, 64);
        zp[r] = 1.0f / (z + 1e-30f);
    }

#pragma unroll
    for (int dt = 0; dt < 4; dt++)
#pragma unroll
        for (int r = 0; r < 4; r++)
            att[(size_t)(b * SEQ + q0 + w * 16 + quad * 4 + r) * HID + hoff +
                dt * 16 + c] = f2bf(acc_o[dt][r] * zp[r]);

    if (c == 0) {
        const size_t zb = (size_t)(b * NHEAD + h) * SEQ + q0 + w * 16 + quad * 4;
#pragma unroll
        for (int r = 0; r < 4; r++) zinv_out[zb + r] = zp[r];
    }
}

// ---------------------------------------------------------------------------
// Pass 2 (MFMA): 128 k-cols/block, 8 waves. colsum_k += sum_q exp(s)*zinv_q.
// K frags + mask bias hoisted out of the q-loop; atomicAdd over heads.
// ---------------------------------------------------------------------------
__global__ __launch_bounds__(512) void colsum_mfma_kernel(
    const unsigned short* __restrict__ qb, const unsigned short* __restrict__ kb,
    const unsigned char* __restrict__ mask, const float* __restrict__ zinv,
    float* __restrict__ colsum)
{
    const int b = blockIdx.z, h = blockIdx.y, k0 = blockIdx.x * 128;
    const int tid = threadIdx.x;
    const int w = tid >> 6, lane = tid & 63;
    const int c = lane & 15, quad = lane >> 4;

    __shared__ unsigned short Ks[128][72];
    __shared__ unsigned short Qs[64][72];
    __shared__ float zs[64];

    const size_t hoff = (size_t)h * DHEAD;
#pragma unroll
    for (int it = 0; it < 2; it++) {
        const int g = it * 512 + tid;
        const int r = g >> 3, c8 = (g & 7) << 3;
        *(uint4*)&Ks[r][c8] =
            *(const uint4*)&kb[(size_t)(b * SEQ + k0 + r) * HID + hoff + c8];
    }
    float mb[4];
#pragma unroll
    for (int r = 0; r < 4; r++)
        mb[r] = mask[(size_t)b * SEQ + k0 + w * 16 + quad * 4 + r] ? -1e9f : 0.f;
    __syncthreads();
    const short8 ak0 = *(const short8*)&Ks[w * 16 + c][quad * 8];
    const short8 ak1 = *(const short8*)&Ks[w * 16 + c][32 + quad * 8];

    float cs[4] = {0.f, 0.f, 0.f, 0.f};
    const size_t zbase = (size_t)(b * NHEAD + h) * SEQ;

    for (int qc = 0; qc < SEQ; qc += 64) {
        __syncthreads();
        {
            const int r = tid >> 3, c8 = (tid & 7) << 3;
            *(uint4*)&Qs[r][c8] =
                *(const uint4*)&qb[(size_t)(b * SEQ + qc + r) * HID + hoff + c8];
        }
        if (tid < 64) zs[tid] = zinv[zbase + qc + tid];
        __syncthreads();

#pragma unroll
        for (int qt = 0; qt < 4; qt++) {
            const short8 bq0 = *(const short8*)&Qs[qt * 16 + c][quad * 8];
            const short8 bq1 = *(const short8*)&Qs[qt * 16 + c][32 + quad * 8];
            floatx4 s = (floatx4){0.f, 0.f, 0.f, 0.f};
            s = MFMA16(ak0, bq0, s);
            s = MFMA16(ak1, bq1, s);
            const float zi = zs[qt * 16 + c];
#pragma unroll
            for (int r = 0; r < 4; r++)
                cs[r] += __expf(fmaf(s[r], QK_SCALE, mb[r])) * zi;
        }
    }

#pragma unroll
    for (int r = 0; r < 4; r++) {
        float v = cs[r];
        v += __shfl_xor(v, 1, 64); v += __shfl_xor(v, 2, 64);
        v += __shfl_xor(v, 4, 64); v += __shfl_xor(v, 8, 64);
        if (c == 0)
            atomicAdd(&colsum[(size_t)b * SEQ + k0 + w * 16 + quad * 4 + r], v);
    }
}

// ---------------------------------------------------------------------------
extern "C" void kernel_launch(void* const* d_in, const int* in_sizes, int n_in,
                              void* d_out, int out_size, void* d_ws, size_t ws_size,
                              hipStream_t stream)
{
    const float* v  = (const float*)d_in[0];
    const float* k  = (const float*)d_in[1];
    const float* q  = (const float*)d_in[2];
    const unsigned char* mask = (const unsigned char*)d_in[3];
    const float* Wv = (const float*)d_in[4];
    const float* bv = (const float*)d_in[5];
    const float* Wk = (const float*)d_in[6];
    const float* bk = (const float*)d_in[7];
    const float* Wq = (const float*)d_in[8];
    const float* bq = (const float*)d_in[9];
    const float* Wt = (const float*)d_in[10];
    const float* bt = (const float*)d_in[11];
    const float* Wm = (const float*)d_in[12];
    const float* bm = (const float*)d_in[13];
    float* out = (float*)d_out;

    const size_t NE = (size_t)MROWS * HID;
    const size_t WE = (size_t)HID * HID;
    unsigned short* qa   = (unsigned short*)d_ws;
    unsigned short* ka   = qa  + NE;
    unsigned short* va   = ka  + NE;
    unsigned short* qp   = va  + NE;
    unsigned short* kp   = qp  + NE;
    unsigned short* vp   = kp  + NE;
    unsigned short* WqT  = vp  + NE;
    unsigned short* WkT  = WqT + WE;
    unsigned short* WvT  = WkT + WE;
    unsigned short* WmT  = WvT + WE;
    float* thr    = (float*)(WmT + WE);
    float* zinv   = thr  + MROWS;
    float* colsum = zinv + (size_t)BATCH * NHEAD * SEQ;
    // buffer reuse (stream-ordered, live ranges don't overlap):
    unsigned short* attb = qa;   // qa dead after q-projection GEMM
    unsigned short* vtb  = ka;   // ka dead after k-projection GEMM

    wtrans_kernel<<<dim3(HID / 64, HID / 64, 4), 256, 0, stream>>>(
        Wq, Wk, Wv, Wm, WqT, WkT, WvT, WmT);

    cvt_bf16_kernel<<<dim3((unsigned)(NE / (256 * 8)), 3), 256, 0, stream>>>(
        q, k, v, qa, ka, va);

    const dim3 gg(MROWS / 128, HID / 128);
    gemm_mfma_kernel<<<gg, 256, 0, stream>>>(qa, WqT, bq, nullptr, nullptr,
                                             nullptr, qp, MROWS, HID, HID);
    gemm_mfma_kernel<<<gg, 256, 0, stream>>>(ka, WkT, bk, nullptr, nullptr,
                                             nullptr, kp, MROWS, HID, HID);
    gemm_mfma_kernel<<<gg, 256, 0, stream>>>(va, WvT, bv, nullptr, nullptr,
                                             nullptr, vp, MROWS, HID, HID);

    vtrans_kernel<<<dim3(SEQ / 64, NHEAD, BATCH), 256, 0, stream>>>(vp, vtb);

    threshold_kernel<<<MROWS / 4, 256, 0, stream>>>(qp, kp, Wt, bt, thr);

    flash_mfma_kernel<<<dim3(SEQ / 128, NHEAD, BATCH), 512, 0, stream>>>(
        qp, kp, vtb, mask, attb, zinv);

    hipMemsetAsync(colsum, 0, MROWS * sizeof(float), stream);
    colsum_mfma_kernel<<<dim3(SEQ / 128, NHEAD, BATCH), 512, 0, stream>>>(
        qp, kp, mask, zinv, colsum);

    gemm_mfma_kernel<<<gg, 256, 0, stream>>>(attb, WmT, bm, colsum, thr,
                                             out, nullptr, MROWS, HID, HID);
}